// Round 12
// baseline (73.853 us; speedup 1.0000x reference)
//
#include <hip/hip_runtime.h>
#include <math.h>

// Problem constants: B=8, CIN=128, COUT=128, H=64, W=64, N=50000, NV=200000, M=800000
constexpr int CIN  = 128;
constexpr int COUT = 128;
constexpr int H    = 64;
constexpr int W    = 64;

typedef __attribute__((ext_vector_type(8))) short short8;   // 8 bf16 (4 VGPR)
typedef __attribute__((ext_vector_type(4))) float f32x4;

__device__ __forceinline__ float bf2f(unsigned short u) {
  union { unsigned i; float f; } c; c.i = (unsigned)u << 16; return c.f;
}
__device__ __forceinline__ float ubits(unsigned u) {
  union { unsigned i; float f; } c; c.i = u; return c.f;
}
__device__ __forceinline__ unsigned short f2bf(float f) {
  union { float f; unsigned i; } c; c.f = f;
  unsigned x = c.i;
  unsigned r = x + 0x7fffu + ((x >> 16) & 1u);   // RNE
  return (unsigned short)(r >> 16);
}

#define GLOAD_LDS16(g, l) __builtin_amdgcn_global_load_lds( \
  (const __attribute__((address_space(1))) unsigned int*)(g), \
  (__attribute__((address_space(3))) unsigned int*)(l), 16, 0, 0)

// ---------------------------------------------------------------------------
// Prep: conv_w f32 [co][ci][3][3] -> Wt2 bf16 [q][co][ci] (k-major). 64 blocks.
// ---------------------------------------------------------------------------
__global__ void prep_kernel(const float* __restrict__ w, unsigned short* __restrict__ wt2) {
  int t = blockIdx.x * 256 + threadIdx.x;        // t = co*128 + ci, 16384 total
  float v[9];
#pragma unroll
  for (int q = 0; q < 9; ++q) v[q] = w[(size_t)t * 9 + q];
#pragma unroll
  for (int q = 0; q < 9; ++q) wt2[q * (COUT * CIN) + t] = f2bf(v[q]);
}

// ---------------------------------------------------------------------------
// Conv 3x3 SAME, implicit GEMM on MFMA bf16 (r4-proven structure) + meta tail.
// Conv blocks (bid < 512): one (b, h0) row; 64 px x 128 co; 4 waves
// (px-half x co-half), M_rep=2 N_rep=4; in-kernel f32->bf16 transpose staging
// of rows h0-1..h0+1 into XOR-swizzled sIn; 9 single-plane weight stages per
// 64-ci chunk via global_load_lds (inverse-swizzled source).
// Meta blocks (bid >= 512): per-point CSR meta (p0, p1, zero-fold flag) —
// consumed only by pool_kernel (launched after conv), so ordering is safe.
// ---------------------------------------------------------------------------
__global__ __launch_bounds__(256, 2)
void conv_mfma_kernel(const float* __restrict__ in, const unsigned short* __restrict__ wt2,
                      const float* __restrict__ bias, unsigned short* __restrict__ feat,
                      const int* __restrict__ aptr, const int* __restrict__ vptr,
                      int2* __restrict__ meta, int N) {
  const int bid = blockIdx.x;
  const int tid = threadIdx.x;

  if (bid >= 512) {
    // ---- meta tail: one point per thread
    int t = (bid - 512) * 256 + tid;
    if (t < N) {
      int v0 = vptr[t], v1 = vptr[t + 1];
      int p0 = aptr[v0], p1 = aptr[v1];
      int e = (v1 == v0) ? 1 : 0;
      int prev = p0;
      for (int v = v0 + 1; v <= v1; ++v) {   // detect empty view segments
        int a = aptr[v];
        if (a == prev) e = 1;
        prev = a;
      }
      meta[t] = make_int2(p0, p1 | (e << 30));
    }
    return;
  }

  __shared__ __align__(16) unsigned short sIn[3 * 66 * 64];  // 25344 B
  __shared__ __align__(16) unsigned short sW[128 * 64];      // 16384 B

  const int lane = tid & 63;
  const int wid  = tid >> 6;
  const int h0   = bid & 63;
  const int b    = bid >> 6;
  const int wave_px = (wid >> 1) * 32;
  const int wave_co = (wid & 1) * 64;
  const int l15  = lane & 15;
  const int kk   = lane >> 4;

  char* sInc = (char*)sIn;
  char* sWc  = (char*)sW;

  f32x4 acc[2][4];
#pragma unroll
  for (int m = 0; m < 2; ++m)
#pragma unroll
    for (int n = 0; n < 4; ++n) acc[m][n] = (f32x4){0.f, 0.f, 0.f, 0.f};

  float bv[4];
#pragma unroll
  for (int n = 0; n < 4; ++n) bv[n] = bias[wave_co + n * 16 + l15];

  for (int i = tid; i < 3 * 64 * 2; i += 256) {   // zero pad columns wp=0,65
    int rr = i >> 7, rem = i & 127;
    int wp = (rem & 1) ? 65 : 0, ci = rem >> 1;
    int byte = rr * 8448 + wp * 128 + ci * 2;
    byte ^= ((wp & 7) << 4);
    *(unsigned short*)(sInc + byte) = 0;
  }

  int swd[4], swsrc[4];
#pragma unroll
  for (int i = 0; i < 4; ++i) {
    int d0 = i * 4096 + wid * 1024 + lane * 16;
    int co = d0 >> 7;
    swd[i]   = d0;
    swsrc[i] = co * 256 + ((d0 & 127) ^ ((co & 7) << 4));
  }
  const char* wt2c = (const char*)wt2;

  for (int chunk = 0; chunk < 2; ++chunk) {
    __syncthreads();
    if (tid < 192) {   // stage input rows h0-1..h0+1, 64 ci, f32 -> bf16 swizzled
      int rr = tid >> 6, cil = tid & 63;
      int ci = cil + chunk * 64;
      int h  = h0 + rr - 1;
      bool valid = (h >= 0) && (h < H);
      const float* src = in + (((size_t)b * CIN + ci) * H + (valid ? h : 0)) * W;
      int base = rr * 8448 + cil * 2;
#pragma unroll
      for (int j = 0; j < 16; ++j) {
        float4 v = valid ? *reinterpret_cast<const float4*>(src + j * 4)
                         : make_float4(0.f, 0.f, 0.f, 0.f);
        const float* ve = (const float*)&v;
#pragma unroll
        for (int e = 0; e < 4; ++e) {
          int wp = j * 4 + e + 1;
          int byte = (base + wp * 128) ^ ((wp & 7) << 4);
          *(unsigned short*)(sInc + byte) = f2bf(ve[e]);
        }
      }
    }

    for (int q = 0; q < 9; ++q) {
      if (q) __syncthreads();
      const char* wq = wt2c + (size_t)q * (COUT * CIN * 2) + chunk * 128;
#pragma unroll
      for (int i = 0; i < 4; ++i)
        GLOAD_LDS16(wq + swsrc[i], sWc + swd[i]);
      __syncthreads();

      const int ky = q / 3, kx = q % 3;
#pragma unroll
      for (int ks = 0; ks < 2; ++ks) {
        const int cil2 = ks * 64 + kk * 16;
        short8 af[2];
#pragma unroll
        for (int m = 0; m < 2; ++m) {
          int wp = wave_px + m * 16 + l15 + kx;
          int byte = (ky * 8448 + wp * 128 + cil2) ^ ((wp & 7) << 4);
          af[m] = *(const short8*)(sInc + byte);
        }
        short8 bf[4];
#pragma unroll
        for (int n = 0; n < 4; ++n) {
          int co = wave_co + n * 16 + l15;
          int byte = (co * 128 + cil2) ^ ((co & 7) << 4);
          bf[n] = *(const short8*)(sWc + byte);
        }
#pragma unroll
        for (int m = 0; m < 2; ++m)
#pragma unroll
          for (int n = 0; n < 4; ++n)
            acc[m][n] = __builtin_amdgcn_mfma_f32_16x16x32_bf16(af[m], bf[n], acc[m][n], 0, 0, 0);
      }
    }
  }

  const size_t pbase = ((size_t)b * H + h0) * W;
#pragma unroll
  for (int m = 0; m < 2; ++m) {
#pragma unroll
    for (int r = 0; r < 4; ++r) {
      int px = wave_px + m * 16 + (lane >> 4) * 4 + r;
      unsigned short* dst = feat + (pbase + px) * COUT;
#pragma unroll
      for (int n = 0; n < 4; ++n) {
        int co = wave_co + n * 16 + l15;
        dst[co] = f2bf(acc[m][n][r] + bv[n]);
      }
    }
  }
}

// ---------------------------------------------------------------------------
// Pool (round-7, best known ~41 us): one wave per point, 4 pixel slots x
// 16 channel-groups (16 B/lane), 4-deep gather pipeline (16 px/iter).
// Tail px clamped to a valid row, masked to bf16 -inf. shfl_xor slot reduce.
// ---------------------------------------------------------------------------
__global__ __launch_bounds__(256, 8)
void pool_kernel(const unsigned short* __restrict__ feat, const float* __restrict__ x3d,
                 const int* __restrict__ pix_idx, const int2* __restrict__ meta,
                 float* __restrict__ out, int N) {
  int n = blockIdx.x * 4 + (threadIdx.x >> 6);
  if (n >= N) return;
  const int lane = threadIdx.x & 63;
  const int slot = lane >> 4;
  const int l15  = lane & 15;

  const int2 mm = meta[n];
  const int p0 = mm.x;
  const int p1 = mm.y & 0x3FFFFFFF;
  const bool zfold = (mm.y & 0x40000000) != 0;

  const size_t o = (size_t)n * COUT + l15 * 8 + slot * 2;
  unsigned long long xb =
      __builtin_nontemporal_load((const unsigned long long*)(x3d + o));

  float acc[8];
#pragma unroll
  for (int j = 0; j < 8; ++j) acc[j] = -INFINITY;

  const char* fb = (const char*)feat + l15 * 16;
  const int last = p1 - 1;

  for (int g = p0; g < p1; g += 16) {
    int pp[4];
    uint4 v[4];
#pragma unroll
    for (int u = 0; u < 4; ++u) {
      pp[u] = g + u * 4 + slot;
      int idx = __builtin_nontemporal_load(pix_idx + min(pp[u], last));
      v[u] = *reinterpret_cast<const uint4*>(fb + (size_t)idx * 256);
    }
#pragma unroll
    for (int u = 0; u < 4; ++u) {
      if (pp[u] > last) { v[u].x = v[u].y = v[u].z = v[u].w = 0xFF80FF80u; }
      const unsigned* w = (const unsigned*)&v[u];
#pragma unroll
      for (int j = 0; j < 4; ++j) {
        acc[2*j]   = fmaxf(acc[2*j],   ubits(w[j] << 16));
        acc[2*j+1] = fmaxf(acc[2*j+1], ubits(w[j] & 0xFFFF0000u));
      }
    }
  }

#pragma unroll
  for (int j = 0; j < 8; ++j) {
    acc[j] = fmaxf(acc[j], __shfl_xor(acc[j], 16, 64));
    acc[j] = fmaxf(acc[j], __shfl_xor(acc[j], 32, 64));
  }
  if (zfold) {
#pragma unroll
    for (int j = 0; j < 8; ++j) acc[j] = fmaxf(acc[j], 0.f);
  }
  // p1==p0 => loop skipped, acc=-inf, zfold guaranteed true -> 0

  union { float f[2]; unsigned long long u; } pk;
  pk.f[0] = ubits((unsigned)xb)         + acc[slot * 2];
  pk.f[1] = ubits((unsigned)(xb >> 32)) + acc[slot * 2 + 1];
  __builtin_nontemporal_store(pk.u, (unsigned long long*)(out + o));
}

extern "C" void kernel_launch(void* const* d_in, const int* in_sizes, int n_in,
                              void* d_out, int out_size, void* d_ws, size_t ws_size,
                              hipStream_t stream) {
  const float* x3d     = (const float*)d_in[0];
  const float* mod_x   = (const float*)d_in[1];
  const float* conv_w  = (const float*)d_in[2];
  const float* conv_b  = (const float*)d_in[3];
  const int*   pix_idx = (const int*)d_in[4];
  const int*   aptr    = (const int*)d_in[5];
  const int*   vptr    = (const int*)d_in[6];
  float*       out     = (float*)d_out;

  int N = in_sizes[6] - 1;   // view_ptr has N+1 entries

  // ws layout: feat bf16 [32768][128] = 8388608 B; Wt2 bf16 294912 B; meta int2 400000 B
  unsigned short* feat = (unsigned short*)d_ws;
  unsigned short* wt2  = (unsigned short*)((char*)d_ws + 8388608);
  int2*           meta = (int2*)((char*)d_ws + 8388608 + 294912);

  prep_kernel<<<64, 256, 0, stream>>>(conv_w, wt2);

  int gconv = 512 + (N + 255) / 256;   // 512 conv blocks + meta tail blocks
  conv_mfma_kernel<<<gconv, 256, 0, stream>>>(mod_x, wt2, conv_b, feat,
                                              aptr, vptr, meta, N);

  pool_kernel<<<(N + 3) / 4, 256, 0, stream>>>(feat, x3d, pix_idx, meta, out, N);
}

// Round 13
// 68.474 us; speedup vs baseline: 1.0786x; 1.0786x over previous
//
#include <hip/hip_runtime.h>
#include <math.h>

// Problem constants: B=8, CIN=128, COUT=128, H=64, W=64, N=50000, NV=200000, M=800000
constexpr int CIN  = 128;
constexpr int COUT = 128;
constexpr int H    = 64;
constexpr int W    = 64;

typedef __attribute__((ext_vector_type(8))) short short8;   // 8 bf16 (4 VGPR)
typedef __attribute__((ext_vector_type(4))) float f32x4;

__device__ __forceinline__ float bf2f(unsigned short u) {
  union { unsigned i; float f; } c; c.i = (unsigned)u << 16; return c.f;
}
__device__ __forceinline__ float ubits(unsigned u) {
  union { unsigned i; float f; } c; c.i = u; return c.f;
}
__device__ __forceinline__ unsigned short f2bf(float f) {
  union { float f; unsigned i; } c; c.f = f;
  unsigned x = c.i;
  unsigned r = x + 0x7fffu + ((x >> 16) & 1u);   // RNE
  return (unsigned short)(r >> 16);
}

#define GLOAD_LDS16(g, l) __builtin_amdgcn_global_load_lds( \
  (const __attribute__((address_space(1))) unsigned int*)(g), \
  (__attribute__((address_space(3))) unsigned int*)(l), 16, 0, 0)

// ---------------------------------------------------------------------------
// Prep (sectioned by blockIdx) — r11-proven:
//  [0, tb)      : NCHW f32 -> NHWC bf16 transpose of mod_x into inT
//  [tb, tb+64)  : conv_w f32 [co][ci][3][3] -> Wt2 bf16 [q][co][ci]
//  [tb+64, ...) : per-point CSR meta (p0, p1, zero-fold flag)
// ---------------------------------------------------------------------------
__global__ void prep_kernel(const float* __restrict__ w, unsigned short* __restrict__ wt2,
                            const int* __restrict__ aptr, const int* __restrict__ vptr,
                            int2* __restrict__ meta, int N,
                            const float* __restrict__ in, unsigned short* __restrict__ inT,
                            int tb) {
  __shared__ __align__(16) unsigned short sT[64 * 128];   // 16 KB bf16 tile
  const int bid = blockIdx.x, tid = threadIdx.x;

  if (bid < tb) {
    // transpose one (b,h) row: [128 ci][64 w] f32 -> [64 w][128 ci] bf16
    const int b = bid >> 6, h = bid & 63;
    char* sc = (char*)sT;
    const int wv = tid >> 6, ln = tid & 63;   // wave id, lane(=w)
#pragma unroll 4
    for (int j = 0; j < 32; ++j) {
      int ci = wv + j * 4;
      float v = in[(((size_t)b * CIN + ci) * H + h) * W + ln];
      int byte = (ln * 256 + ci * 2) ^ ((ln & 7) << 4);
      *(unsigned short*)(sc + byte) = f2bf(v);
    }
    __syncthreads();
    const int ww = tid >> 2, cg = tid & 3;
    const size_t pix = ((size_t)b * H + h) * W + ww;
#pragma unroll
    for (int j = 0; j < 4; ++j) {
      int byte = (ww * 256 + cg * 64 + j * 16) ^ ((ww & 7) << 4);
      short8 v = *(const short8*)(sc + byte);
      *(short8*)((char*)inT + pix * 256 + cg * 64 + j * 16) = v;
    }
    return;
  }

  if (bid < tb + 64) {
    int t = (bid - tb) * 256 + tid;
    float v[9];
#pragma unroll
    for (int q = 0; q < 9; ++q) v[q] = w[(size_t)t * 9 + q];
#pragma unroll
    for (int q = 0; q < 9; ++q) wt2[q * (COUT * CIN) + t] = f2bf(v[q]);
    return;
  }

  int t = (bid - tb - 64) * 256 + tid;
  if (t < N) {
    int v0 = vptr[t], v1 = vptr[t + 1];
    int p0 = aptr[v0], p1 = aptr[v1];
    int e = (v1 == v0) ? 1 : 0;
    int prev = p0;
    for (int v = v0 + 1; v <= v1; ++v) {   // detect empty view segments
      int a = aptr[v];
      if (a == prev) e = 1;
      prev = a;
    }
    meta[t] = make_int2(p0, p1 | (e << 30));
  }
}

// ---------------------------------------------------------------------------
// Conv 3x3 SAME, implicit GEMM on MFMA bf16 — r11 structure (1-row blocks,
// 512 = 2 blocks/CU, input from pre-transposed inT via global_load_lds) with
// 2-plane weight staging: sW holds 2 q-planes (32 KB), 5 stages per chunk
// -> 10 barrier/drain pairs per block (was 18), 32 MFMA/wave per barrier.
// LDS 58112 B dynamic: sIn [3 rr][66 wp][64 ci] swizzled (25344 B) + sW.
// ---------------------------------------------------------------------------
__global__ __launch_bounds__(256)
void conv_mfma_kernel(const unsigned short* __restrict__ inT,
                      const unsigned short* __restrict__ wt2,
                      const float* __restrict__ bias, unsigned short* __restrict__ feat) {
  extern __shared__ __align__(16) char smem[];
  char* sInc = smem;                  // 25344 B
  char* sWc  = smem + 25344;          // 32768 B (2 planes)

  const int tid  = threadIdx.x;
  const int lane = tid & 63;
  const int wid  = tid >> 6;
  const int h0   = blockIdx.x;        // 0..63
  const int b    = blockIdx.y;
  const int wave_px = (wid >> 1) * 32;
  const int wave_co = (wid & 1) * 64;
  const int l15  = lane & 15;
  const int kk   = lane >> 4;         // k-subgroup 0..3

  f32x4 acc[2][4];
#pragma unroll
  for (int m = 0; m < 2; ++m)
#pragma unroll
    for (int n = 0; n < 4; ++n) acc[m][n] = (f32x4){0.f, 0.f, 0.f, 0.f};

  float bv[4];
#pragma unroll
  for (int n = 0; n < 4; ++n) bv[n] = bias[wave_co + n * 16 + l15];

  // zero pad columns wp=0 and wp=65 for the 3 rows (stay zero)
  for (int i = tid; i < 3 * 64 * 2; i += 256) {
    int rr = i >> 7, rem = i & 127;
    int wp = (rem & 1) ? 65 : 0, ci = rem >> 1;
    int byte = rr * 8448 + wp * 128 + ci * 2;
    byte ^= ((wp & 7) << 4);
    *(unsigned short*)(sInc + byte) = 0;
  }
  // zero OOB rows fully (never staged -> stay zero)
  const uint4 z4 = make_uint4(0, 0, 0, 0);
  if (h0 == 0)
    for (int i = tid; i < 528; i += 256) *(uint4*)(sInc + i * 16) = z4;            // rr=0 (h=-1)
  if (h0 == H - 1)
    for (int i = tid; i < 528; i += 256) *(uint4*)(sInc + 2 * 8448 + i * 16) = z4; // rr=2 (h=64)

  // weight staging pattern (16 KB q-plane): linear LDS dst, inv-swizzled src
  int swd[4], swsrc[4];
#pragma unroll
  for (int i = 0; i < 4; ++i) {
    int d0 = i * 4096 + wid * 1024 + lane * 16;
    int co = d0 >> 7;
    swd[i]   = d0;
    swsrc[i] = co * 256 + ((d0 & 127) ^ ((co & 7) << 4));
  }
  const char* wt2c = (const char*)wt2;
  const char* inTc = (const char*)inT;

  for (int chunk = 0; chunk < 2; ++chunk) {
    __syncthreads();   // readers of sIn / last sW stage done before overwrite
    // stage input rows h0-1..h0+1 (valid ones): 6 rounds x 256 thr x 16 B = 24 KB
#pragma unroll
    for (int r6 = 0; r6 < 6; ++r6) {
      int d  = r6 * 4096 + tid * 16;
      int rr = d >> 13;                       // uniform per round
      int h  = h0 + rr - 1;
      if (h >= 0 && h < H) {
        int rem   = d & 8191;
        int wp    = 1 + (rem >> 7);
        int inner = d & 127;
        size_t pix = ((size_t)b * H + h) * W + (wp - 1);
        GLOAD_LDS16(inTc + pix * 256 + chunk * 128 + (inner ^ ((wp & 7) << 4)),
                    sInc + rr * 8448 + 128 + rem);
      }
    }

    for (int qs = 0; qs < 5; ++qs) {
      const int nq = (qs < 4) ? 2 : 1;
      if (qs) __syncthreads();       // previous stage's sW readers done
      for (int qp = 0; qp < nq; ++qp) {
        const char* wq = wt2c + (size_t)(qs * 2 + qp) * (COUT * CIN * 2) + chunk * 128;
#pragma unroll
        for (int i = 0; i < 4; ++i)
          GLOAD_LDS16(wq + swsrc[i], sWc + qp * 16384 + swd[i]);
      }
      __syncthreads();               // drains vmcnt (input + weights)

      for (int qp = 0; qp < nq; ++qp) {
        const int q  = qs * 2 + qp;
        const int ky = q / 3, kx = q % 3;
#pragma unroll
        for (int ks = 0; ks < 2; ++ks) {
          const int cil2 = ks * 64 + kk * 16;   // byte offset of lane's k-slice
          short8 af[2];
#pragma unroll
          for (int m = 0; m < 2; ++m) {
            int wp = wave_px + m * 16 + l15 + kx;
            int byte = (ky * 8448 + wp * 128 + cil2) ^ ((wp & 7) << 4);
            af[m] = *(const short8*)(sInc + byte);
          }
          short8 bf[4];
#pragma unroll
          for (int n = 0; n < 4; ++n) {
            int co = wave_co + n * 16 + l15;
            int byte = (qp * 16384 + co * 128 + cil2) ^ ((co & 7) << 4);
            bf[n] = *(const short8*)(sWc + byte);
          }
#pragma unroll
          for (int m = 0; m < 2; ++m)
#pragma unroll
            for (int n = 0; n < 4; ++n)
              acc[m][n] = __builtin_amdgcn_mfma_f32_16x16x32_bf16(af[m], bf[n], acc[m][n], 0, 0, 0);
        }
      }
    }
  }

  // epilogue: bias add, bf16 round, NHWC feat write
  const size_t pbase = ((size_t)b * H + h0) * W;
#pragma unroll
  for (int m = 0; m < 2; ++m) {
#pragma unroll
    for (int r = 0; r < 4; ++r) {
      int px = wave_px + m * 16 + (lane >> 4) * 4 + r;
      unsigned short* dst = feat + (pbase + px) * COUT;
#pragma unroll
      for (int n = 0; n < 4; ++n) {
        int co = wave_co + n * 16 + l15;
        dst[co] = f2bf(acc[m][n][r] + bv[n]);
      }
    }
  }
}

// ---------------------------------------------------------------------------
// Legacy conv (round-9, proven): in-kernel f32->bf16 transpose staging.
// Launched only if ws_size is too small for the inT table.
// ---------------------------------------------------------------------------
__global__ __launch_bounds__(256)
void conv_mfma_legacy(const float* __restrict__ in, const unsigned short* __restrict__ wt2,
                      const float* __restrict__ bias, unsigned short* __restrict__ feat) {
  extern __shared__ __align__(16) char smem[];
  char* sInc = smem;
  char* sWc  = smem + 33792;

  const int tid  = threadIdx.x;
  const int lane = tid & 63;
  const int wid  = tid >> 6;
  const int h0   = blockIdx.x * 2;
  const int b    = blockIdx.y;
  const int wrow    = wid >> 1;
  const int wave_co = (wid & 1) * 64;
  const int l15  = lane & 15;
  const int kk   = lane >> 4;

  f32x4 acc[4][4];
#pragma unroll
  for (int m = 0; m < 4; ++m)
#pragma unroll
    for (int n = 0; n < 4; ++n) acc[m][n] = (f32x4){0.f, 0.f, 0.f, 0.f};

  float bv[4];
#pragma unroll
  for (int n = 0; n < 4; ++n) bv[n] = bias[wave_co + n * 16 + l15];

  for (int i = tid; i < 4 * 64 * 2; i += 256) {
    int rr = i >> 7, rem = i & 127;
    int wp = (rem & 1) ? 65 : 0, ci = rem >> 1;
    int byte = rr * 8448 + wp * 128 + ci * 2;
    byte ^= ((wp & 7) << 4);
    *(unsigned short*)(sInc + byte) = 0;
  }

  int swd[4], swsrc[4];
#pragma unroll
  for (int i = 0; i < 4; ++i) {
    int d0 = i * 4096 + wid * 1024 + lane * 16;
    int co = d0 >> 7;
    swd[i]   = d0;
    swsrc[i] = co * 256 + ((d0 & 127) ^ ((co & 7) << 4));
  }
  const char* wt2c = (const char*)wt2;

  for (int chunk = 0; chunk < 2; ++chunk) {
    __syncthreads();
    {
      int rr = tid >> 6, cil = tid & 63;
      int ci = cil + chunk * 64;
      int h  = h0 + rr - 1;
      bool valid = (h >= 0) && (h < H);
      const float* src = in + (((size_t)b * CIN + ci) * H + (valid ? h : 0)) * W;
      int base = rr * 8448 + cil * 2;
#pragma unroll
      for (int j = 0; j < 16; ++j) {
        float4 v = valid ? *reinterpret_cast<const float4*>(src + j * 4)
                         : make_float4(0.f, 0.f, 0.f, 0.f);
        const float* ve = (const float*)&v;
#pragma unroll
        for (int e = 0; e < 4; ++e) {
          int wp = j * 4 + e + 1;
          int byte = (base + wp * 128) ^ ((wp & 7) << 4);
          *(unsigned short*)(sInc + byte) = f2bf(ve[e]);
        }
      }
    }
    for (int qs = 0; qs < 5; ++qs) {
      const int nq = (qs < 4) ? 2 : 1;
      if (qs) __syncthreads();
      for (int qp = 0; qp < nq; ++qp) {
        const char* wq = wt2c + (size_t)(qs * 2 + qp) * (COUT * CIN * 2) + chunk * 128;
#pragma unroll
        for (int i = 0; i < 4; ++i)
          GLOAD_LDS16(wq + swsrc[i], sWc + qp * 16384 + swd[i]);
      }
      __syncthreads();
      for (int qp = 0; qp < nq; ++qp) {
        const int q  = qs * 2 + qp;
        const int ky = q / 3, kx = q % 3;
#pragma unroll
        for (int ks = 0; ks < 2; ++ks) {
          const int cil2 = ks * 64 + kk * 16;
          short8 af[4];
#pragma unroll
          for (int m = 0; m < 4; ++m) {
            int wp = m * 16 + l15 + kx;
            int byte = ((wrow + ky) * 8448 + wp * 128 + cil2) ^ ((wp & 7) << 4);
            af[m] = *(const short8*)(sInc + byte);
          }
          short8 bf[4];
#pragma unroll
          for (int n = 0; n < 4; ++n) {
            int co = wave_co + n * 16 + l15;
            int byte = (qp * 16384 + co * 128 + cil2) ^ ((co & 7) << 4);
            bf[n] = *(const short8*)(sWc + byte);
          }
#pragma unroll
          for (int m = 0; m < 4; ++m)
#pragma unroll
            for (int n = 0; n < 4; ++n)
              acc[m][n] = __builtin_amdgcn_mfma_f32_16x16x32_bf16(af[m], bf[n], acc[m][n], 0, 0, 0);
        }
      }
    }
  }

  const size_t pbase = ((size_t)b * H + (h0 + wrow)) * W;
#pragma unroll
  for (int m = 0; m < 4; ++m) {
#pragma unroll
    for (int r = 0; r < 4; ++r) {
      int px = m * 16 + (lane >> 4) * 4 + r;
      unsigned short* dst = feat + (pbase + px) * COUT;
#pragma unroll
      for (int n = 0; n < 4; ++n) {
        int co = wave_co + n * 16 + l15;
        dst[co] = f2bf(acc[m][n][r] + bv[n]);
      }
    }
  }
}

// ---------------------------------------------------------------------------
// Pool (round-7, best known ~41 us): one wave per point, 4 pixel slots x
// 16 channel-groups (16 B/lane), 4-deep gather pipeline (16 px/iter).
// ---------------------------------------------------------------------------
__global__ __launch_bounds__(256, 8)
void pool_kernel(const unsigned short* __restrict__ feat, const float* __restrict__ x3d,
                 const int* __restrict__ pix_idx, const int2* __restrict__ meta,
                 float* __restrict__ out, int N) {
  int n = blockIdx.x * 4 + (threadIdx.x >> 6);
  if (n >= N) return;
  const int lane = threadIdx.x & 63;
  const int slot = lane >> 4;
  const int l15  = lane & 15;

  const int2 mm = meta[n];
  const int p0 = mm.x;
  const int p1 = mm.y & 0x3FFFFFFF;
  const bool zfold = (mm.y & 0x40000000) != 0;

  const size_t o = (size_t)n * COUT + l15 * 8 + slot * 2;
  unsigned long long xb =
      __builtin_nontemporal_load((const unsigned long long*)(x3d + o));

  float acc[8];
#pragma unroll
  for (int j = 0; j < 8; ++j) acc[j] = -INFINITY;

  const char* fb = (const char*)feat + l15 * 16;
  const int last = p1 - 1;

  for (int g = p0; g < p1; g += 16) {
    int pp[4];
    uint4 v[4];
#pragma unroll
    for (int u = 0; u < 4; ++u) {
      pp[u] = g + u * 4 + slot;
      int idx = __builtin_nontemporal_load(pix_idx + min(pp[u], last));
      v[u] = *reinterpret_cast<const uint4*>(fb + (size_t)idx * 256);
    }
#pragma unroll
    for (int u = 0; u < 4; ++u) {
      if (pp[u] > last) { v[u].x = v[u].y = v[u].z = v[u].w = 0xFF80FF80u; }
      const unsigned* w = (const unsigned*)&v[u];
#pragma unroll
      for (int j = 0; j < 4; ++j) {
        acc[2*j]   = fmaxf(acc[2*j],   ubits(w[j] << 16));
        acc[2*j+1] = fmaxf(acc[2*j+1], ubits(w[j] & 0xFFFF0000u));
      }
    }
  }

#pragma unroll
  for (int j = 0; j < 8; ++j) {
    acc[j] = fmaxf(acc[j], __shfl_xor(acc[j], 16, 64));
    acc[j] = fmaxf(acc[j], __shfl_xor(acc[j], 32, 64));
  }
  if (zfold) {
#pragma unroll
    for (int j = 0; j < 8; ++j) acc[j] = fmaxf(acc[j], 0.f);
  }

  union { float f[2]; unsigned long long u; } pk;
  pk.f[0] = ubits((unsigned)xb)         + acc[slot * 2];
  pk.f[1] = ubits((unsigned)(xb >> 32)) + acc[slot * 2 + 1];
  __builtin_nontemporal_store(pk.u, (unsigned long long*)(out + o));
}

extern "C" void kernel_launch(void* const* d_in, const int* in_sizes, int n_in,
                              void* d_out, int out_size, void* d_ws, size_t ws_size,
                              hipStream_t stream) {
  const float* x3d     = (const float*)d_in[0];
  const float* mod_x   = (const float*)d_in[1];
  const float* conv_w  = (const float*)d_in[2];
  const float* conv_b  = (const float*)d_in[3];
  const int*   pix_idx = (const int*)d_in[4];
  const int*   aptr    = (const int*)d_in[5];
  const int*   vptr    = (const int*)d_in[6];
  float*       out     = (float*)d_out;

  int N = in_sizes[6] - 1;   // view_ptr has N+1 entries

  // ws layout: feat 8388608 | wt2 294912 | meta 400000 | inT 8388608  (17.47 MB)
  unsigned short* feat = (unsigned short*)d_ws;
  unsigned short* wt2  = (unsigned short*)((char*)d_ws + 8388608);
  int2*           meta = (int2*)((char*)d_ws + 8388608 + 294912);
  unsigned short* inT  = (unsigned short*)((char*)d_ws + 9083520);
  const size_t need = 9083520ull + 8388608ull;
  const bool fast = (ws_size >= need);

  const int tb = fast ? 512 : 0;                       // transpose blocks
  const int gp = tb + 64 + (N + 255) / 256;
  prep_kernel<<<gp, 256, 0, stream>>>(conv_w, wt2, aptr, vptr, meta, N, mod_x, inT, tb);

  if (fast) {
    dim3 gc(64, 8);   // 1-row blocks: 512 -> 2 blocks/CU
    conv_mfma_kernel<<<gc, 256, 58112, stream>>>(inT, wt2, conv_b, feat);
  } else {
    dim3 gc(32, 8);
    conv_mfma_legacy<<<gc, 256, 66560, stream>>>(mod_x, wt2, conv_b, feat);
  }

  pool_kernel<<<(N + 3) / 4, 256, 0, stream>>>(feat, x3d, pix_idx, meta, out, N);
}